// Round 9
// baseline (1064.477 us; speedup 1.0000x reference)
//
#include <hip/hip_runtime.h>
#include <hip/hip_fp16.h>
#include <hip/hip_cooperative_groups.h>

namespace cg = cooperative_groups;

#define ND 25000
#define NG 20000
#define NTOT (ND + NG)      // 45000
#define NBLKH 384           // hist/fill slices PER NODE TYPE (2*NBLKH = 768 = GRID)
#define GRID 768            // 3 blocks/CU * 256 CUs (LDS 50176 B/block -> exactly 3/CU)

typedef _Float16 half8 __attribute__((ext_vector_type(8)));
typedef float f32x4 __attribute__((ext_vector_type(4)));
typedef float f32x2 __attribute__((ext_vector_type(2)));

// ---- workspace layout (bytes), 256B-aligned ----
#define OFF_CNT    0ull           // NTOT int (180000)
#define OFF_ROW    180224ull      // NTOT+1 int
#define OFF_BSUM   360448ull      // 44 int
#define OFF_PARTD  360704ull      // NBLKH*ND u16 (19,200,000)
#define OFF_PARTG  19560704ull    // NBLKH*NG u16 (15,360,000)
#define OFF_COL    34920704ull    // 2*NE u16 (4,000,000)
#define OFF_WSW    38920704ull    // 8*128*128 half (262,144)
#define OFF_XDH    39182848ull    // ND*128 half (6,400,000)
#define OFF_XGH    45582848ull    // NG*128 half (5,120,000)
#define OFF_X8D    50702848ull    // ND*128 fp8 (3,200,000)
#define OFF_X8G    53902848ull    // NG*128 fp8 (2,560,000)
#define OFF_MDH    56462848ull    // ND*128 half (6,400,000)
#define OFF_MGH    62862848ull    // NG*128 half (5,120,000)
#define OFF_D1H    67982848ull    // ND*128 half (6,400,000)
#define OFF_G1H    74382848ull    // NG*128 half (5,120,000)
#define OFF_D18    79502848ull    // ND*128 fp8 (3,200,000)
#define OFF_G18    82702848ull    // NG*128 fp8 (2,560,000)  (end ~85.3 MB)

struct P {
    const float *xd, *xg;
    const int *src, *dst;
    const float *w[8];                       // w1_dg_l, w1_dg_r, w1_gd_l, w1_gd_r, w2_*...
    const float *b1gd, *b1dg, *b2gd, *b2dg;
    int *cnt, *row, *bsum;
    unsigned short *partD, *partG, *col;
    _Float16 *wsw;
    __half *xdh, *xgh, *mdh, *mgh, *d1h, *g1h;
    unsigned char *x8d, *x8g, *d18, *g18;
    float *outd, *outg;
    int E;
};

// ---------------- phase 0a: f32 -> {f16,fp8} convert + weight swizzle ----------------------------
__device__ void ph_prep(const P& p, int bx, int t) {
    const int ndq = ND * 32;
    const int tot = ndq + NG * 32;
    for (int i = bx * 256 + t; i < tot; i += GRID * 256) {
        const float* x;
        __half* y;
        unsigned char* y8;
        int idx;
        if (i < ndq) { x = p.xd; y = p.xdh; y8 = p.x8d; idx = i; }
        else         { x = p.xg; y = p.xgh; y8 = p.x8g; idx = i - ndq; }
        float4 v = ((const float4*)x)[idx];
        ((__half2*)y)[idx * 2 + 0] = __floats2half2_rn(v.x, v.y);
        ((__half2*)y)[idx * 2 + 1] = __floats2half2_rn(v.z, v.w);
        int p8 = __builtin_amdgcn_cvt_pk_fp8_f32(v.x, v.y, 0, false);
        p8 = __builtin_amdgcn_cvt_pk_fp8_f32(v.z, v.w, p8, true);
        ((int*)y8)[idx] = p8;
    }
    if (bx < 8) {    // W swizzle: slot=(ntile*4+kc)*64+lane; elem j = W[kc*32+(lane>>4)*8+j][ntile*16+(lane&15)]
        const float* W = p.w[bx];
        _Float16* o = p.wsw + (size_t)bx * 16384;
        for (int rep = 0; rep < 8; ++rep) {
            int slot = rep * 256 + t;
            int lane = slot & 63, grp = slot >> 6;
            int kc = grp & 3, ntile = grp >> 2;
            int nn = ntile * 16 + (lane & 15);
            int kb = kc * 32 + (lane >> 4) * 8;
            half8 v;
#pragma unroll
            for (int j = 0; j < 8; ++j) v[j] = (_Float16)W[(size_t)(kb + j) * 128 + nn];
            *(half8*)(o + (size_t)slot * 8) = v;
        }
    }
}

// ---------------- phase 0b: privatized histogram (blocks [0,NBLKH)=disease, rest=gene) -----------
__device__ void ph_hist(const P& p, int bx, int t, unsigned int* h) {
    bool isD = bx < NBLKH;
    int bb = isD ? bx : bx - NBLKH;
    const int* key = isD ? p.src : p.dst;
    int nw = isD ? (ND / 2) : (NG / 2);
    for (int i = t; i < nw; i += 256) h[i] = 0;
    __syncthreads();
    int e0 = (int)(((long long)p.E * bb) / NBLKH);
    int e1 = (int)(((long long)p.E * (bb + 1)) / NBLKH);
    for (int e = e0 + t; e < e1; e += 256) {
        int k = key[e];
        atomicAdd(&h[k >> 1], 1u << ((k & 1) * 16));
    }
    __syncthreads();
    unsigned int* po = (unsigned int*)((isD ? p.partD : p.partG) + (size_t)bb * (isD ? ND : NG));
    for (int i = t; i < nw; i += 256) po[i] = h[i];
}

// ---------------- phase 1: column scan over partials (block-tiled: 64 cols x 4 segs) -------------
__device__ void ph_colscan(const P& p, int bx, int t, unsigned int* lds) {
    if (bx >= (NTOT + 63) / 64) return;       // 704 active blocks
    int cl = t & 63, seg = t >> 2 >> 4;       // seg = t>>6
    int c = bx * 64 + cl;
    bool valid = c < NTOT;
    unsigned short* part;
    int nb, kk;
    if (c < ND) { part = p.partD; nb = ND; kk = c; }
    else        { part = p.partG; nb = NG; kk = c - ND; }
    const int RPS = NBLKH / 4;                // 96 rows per segment
    int r0 = seg * RPS;
    int sum = 0;
    if (valid)
        for (int r = r0; r < r0 + RPS; ++r) sum += part[(size_t)r * nb + kk];
    lds[seg * 64 + cl] = (unsigned int)sum;
    __syncthreads();
    int base = 0;
    for (int s2 = 0; s2 < seg; ++s2) base += (int)lds[s2 * 64 + cl];
    if (valid) {
        int run = base;
        for (int r = r0; r < r0 + RPS; ++r) {
            size_t idx = (size_t)r * nb + kk;
            int v = part[idx];
            part[idx] = (unsigned short)run;
            run += v;
        }
        if (seg == 3) p.cnt[c] = run;
    }
}

// ---------------- phase 2: row-ptr scan pass 1 (44 blocks x 1024 elems) --------------------------
__device__ void ph_scan1(const P& p, int bx, int t, int* sd) {
    if (bx >= 44) return;
    int base = bx * 1024 + t * 4;
    int v[4];
#pragma unroll
    for (int j = 0; j < 4; ++j) {
        int idx = base + j;
        v[j] = (idx < NTOT) ? p.cnt[idx] : 0;
    }
    int tsum = v[0] + v[1] + v[2] + v[3];
    sd[t] = tsum;
    __syncthreads();
    for (int off = 1; off < 256; off <<= 1) {
        int x = (t >= off) ? sd[t - off] : 0;
        __syncthreads();
        sd[t] += x;
        __syncthreads();
    }
    int run = sd[t] - tsum;
#pragma unroll
    for (int j = 0; j < 4; ++j) {
        int idx = base + j;
        if (idx < NTOT) p.row[idx] = run;
        run += v[j];
    }
    if (t == 255) p.bsum[bx] = sd[255];
}

// ---------------- phase 3: row-ptr scan pass 2 ---------------------------------------------------
__device__ void ph_scan2(const P& p, int bx, int t) {
    if (bx >= 44) return;
    int off = 0;
    for (int b2 = 0; b2 < bx; ++b2) off += p.bsum[b2];
    int base = bx * 1024 + t * 4;
#pragma unroll
    for (int j = 0; j < 4; ++j) {
        int idx = base + j;
        if (idx < NTOT) p.row[idx] += off;
    }
    if (bx == 0 && t == 0) p.row[NTOT] = 2 * p.E;
}

// ---------------- phase 4: atomic-free CSR fill --------------------------------------------------
__device__ void ph_fill(const P& p, int bx, int t, unsigned int* h) {
    bool isD = bx < NBLKH;
    int bb = isD ? bx : bx - NBLKH;
    const int* key = isD ? p.src : p.dst;
    const int* val = isD ? p.dst : p.src;
    const int* rowp = isD ? p.row : p.row + ND;
    int nw = isD ? (ND / 2) : (NG / 2);
    const unsigned int* pi =
        (const unsigned int*)((isD ? p.partD : p.partG) + (size_t)bb * (isD ? ND : NG));
    for (int i = t; i < nw; i += 256) h[i] = pi[i];
    __syncthreads();
    int e0 = (int)(((long long)p.E * bb) / NBLKH);
    int e1 = (int)(((long long)p.E * (bb + 1)) / NBLKH);
    for (int e = e0 + t; e < e1; e += 256) {
        int k = key[e];
        int v = val[e];
        unsigned int old = atomicAdd(&h[k >> 1], 1u << ((k & 1) * 16));
        int rank = (old >> ((k & 1) * 16)) & 0xffff;
        p.col[rowp[k] + rank] = (unsigned short)v;
    }
    __syncthreads();   // protect LDS before any later reuse
}

// ---------------- phases 5/7: fp8 mean aggregation (one wave per node, persistent loop) ----------
__device__ void ph_agg(const P& p, const unsigned char* Xg, const unsigned char* Xd,
                       __half* outd, __half* outg, int bx, int t) {
    int wid = t >> 6, lane = t & 63;
    int g = lane >> 3, f = lane & 7;
    for (int node = bx * 4 + wid; node < NTOT; node += GRID * 4) {
        const unsigned char* X;
        _Float16* out;
        int nloc;
        if (node < ND) { X = Xg; out = (_Float16*)outd; nloc = node; }
        else           { X = Xd; out = (_Float16*)outg; nloc = node - ND; }
        int b = p.row[node], e = p.row[node + 1];
        float acc[16];
#pragma unroll
        for (int k = 0; k < 16; ++k) acc[k] = 0.f;
        int j = b + g;
        for (; j + 8 < e; j += 16) {
            int c0 = p.col[j], c1 = p.col[j + 8];
            int4 w0 = *(const int4*)(X + (size_t)c0 * 128 + f * 16);
            int4 w1 = *(const int4*)(X + (size_t)c1 * 128 + f * 16);
            const int* wa = (const int*)&w0;
            const int* wb = (const int*)&w1;
#pragma unroll
            for (int q = 0; q < 4; ++q) {
                f32x2 l0 = __builtin_amdgcn_cvt_pk_f32_fp8(wa[q], false);
                f32x2 h0 = __builtin_amdgcn_cvt_pk_f32_fp8(wa[q], true);
                f32x2 l1 = __builtin_amdgcn_cvt_pk_f32_fp8(wb[q], false);
                f32x2 h1 = __builtin_amdgcn_cvt_pk_f32_fp8(wb[q], true);
                acc[q * 4 + 0] += l0[0] + l1[0];
                acc[q * 4 + 1] += l0[1] + l1[1];
                acc[q * 4 + 2] += h0[0] + h1[0];
                acc[q * 4 + 3] += h0[1] + h1[1];
            }
        }
        if (j < e) {
            int c = p.col[j];
            int4 w = *(const int4*)(X + (size_t)c * 128 + f * 16);
            const int* wa = (const int*)&w;
#pragma unroll
            for (int q = 0; q < 4; ++q) {
                f32x2 l = __builtin_amdgcn_cvt_pk_f32_fp8(wa[q], false);
                f32x2 h = __builtin_amdgcn_cvt_pk_f32_fp8(wa[q], true);
                acc[q * 4 + 0] += l[0];
                acc[q * 4 + 1] += l[1];
                acc[q * 4 + 2] += h[0];
                acc[q * 4 + 3] += h[1];
            }
        }
#pragma unroll
        for (int k = 0; k < 16; ++k) {
            acc[k] += __shfl_xor(acc[k], 8, 64);
            acc[k] += __shfl_xor(acc[k], 16, 64);
            acc[k] += __shfl_xor(acc[k], 32, 64);
        }
        if (g == 0) {
            int deg = e - b;
            float r = 1.0f / (float)(deg > 0 ? deg : 1);
            half8 o0, o1;
#pragma unroll
            for (int k = 0; k < 8; ++k) o0[k] = (_Float16)(acc[k] * r);
#pragma unroll
            for (int k = 0; k < 8; ++k) o1[k] = (_Float16)(acc[8 + k] * r);
            _Float16* op = out + (size_t)nloc * 128 + f * 16;
            *(half8*)op = o0;
            *(half8*)(op + 8) = o1;
        }
    }
}

// ---------------- phases 6/8: MFMA dual GEMM Y = A1@W1 + A2@W2 + b -------------------------------
__device__ void ph_gemm(const P& p, int bx, int t, int layer) {
    const int nblkD = (ND + 63) / 64, nblkG = (NG + 63) / 64;  // 391 + 313 = 704
    if (bx >= nblkD + nblkG) return;
    bool isD = bx < nblkD;
    int n = isD ? ND : NG, b0 = isD ? bx : bx - nblkD;
    const __half *A1, *A2;
    const _Float16 *W1, *W2;
    const float* bias;
    float* Yf = nullptr;
    __half* Yh = nullptr;
    unsigned char* Y8 = nullptr;
    if (layer == 1) {
        if (isD) { A1 = p.mdh; A2 = p.xdh; W1 = p.wsw + 2 * 16384; W2 = p.wsw + 3 * 16384;
                   bias = p.b1gd; Yh = p.d1h; Y8 = p.d18; }
        else     { A1 = p.mgh; A2 = p.xgh; W1 = p.wsw + 0 * 16384; W2 = p.wsw + 1 * 16384;
                   bias = p.b1dg; Yh = p.g1h; Y8 = p.g18; }
    } else {
        if (isD) { A1 = p.mdh; A2 = p.d1h; W1 = p.wsw + 6 * 16384; W2 = p.wsw + 7 * 16384;
                   bias = p.b2gd; Yf = p.outd; }
        else     { A1 = p.mgh; A2 = p.g1h; W1 = p.wsw + 4 * 16384; W2 = p.wsw + 5 * 16384;
                   bias = p.b2dg; Yf = p.outg; }
    }
    int wave = t >> 6, lane = t & 63;
    int row0 = b0 * 64 + wave * 16;
    if (row0 >= n) return;
    int m = lane & 15, quad = lane >> 4;
    int arow = row0 + m;
    if (arow >= n) arow = n - 1;
    const _Float16* a1p = (const _Float16*)A1 + (size_t)arow * 128 + quad * 8;
    const _Float16* a2p = (const _Float16*)A2 + (size_t)arow * 128 + quad * 8;
    half8 a1[4], a2[4];
#pragma unroll
    for (int kc = 0; kc < 4; ++kc) {
        a1[kc] = *(const half8*)(a1p + kc * 32);
        a2[kc] = *(const half8*)(a2p + kc * 32);
    }
#pragma unroll
    for (int ntile = 0; ntile < 8; ++ntile) {
        f32x4 acc = {0.f, 0.f, 0.f, 0.f};
#pragma unroll
        for (int kc = 0; kc < 4; ++kc) {
            half8 b1 = *(const half8*)(W1 + (size_t)((ntile * 4 + kc) * 64 + lane) * 8);
            acc = __builtin_amdgcn_mfma_f32_16x16x32_f16(a1[kc], b1, acc, 0, 0, 0);
            half8 b2 = *(const half8*)(W2 + (size_t)((ntile * 4 + kc) * 64 + lane) * 8);
            acc = __builtin_amdgcn_mfma_f32_16x16x32_f16(a2[kc], b2, acc, 0, 0, 0);
        }
        int colx = ntile * 16 + m;
        float bb = bias[colx];
#pragma unroll
        for (int r = 0; r < 4; ++r) {
            int rr = row0 + quad * 4 + r;
            if (rr < n) {
                float v = acc[r] + bb;
                if (layer == 2) {
                    Yf[(size_t)rr * 128 + colx] = v;
                } else {
                    Yh[(size_t)rr * 128 + colx] = __float2half(v);
                    int p8 = __builtin_amdgcn_cvt_pk_fp8_f32(v, v, 0, false);
                    Y8[(size_t)rr * 128 + colx] = (unsigned char)(p8 & 0xff);
                }
            }
        }
    }
}

// ---------------- the mega kernel ----------------------------------------------------------------
// phase = -1: cooperative, runs all phases with grid.sync. phase >= 0: run one phase (fallback).
__global__ __launch_bounds__(256, 3) void mega(P p, int phase) {
    __shared__ unsigned int lds[12544];      // 50176 B -> exactly 3 blocks/CU
    int bx = blockIdx.x, t = threadIdx.x;
    if (phase < 0) {
        cg::grid_group g = cg::this_grid();
        ph_prep(p, bx, t);
        ph_hist(p, bx, t, lds);
        g.sync();
        ph_colscan(p, bx, t, lds);
        g.sync();
        ph_scan1(p, bx, t, (int*)lds);
        g.sync();
        ph_scan2(p, bx, t);
        g.sync();
        ph_fill(p, bx, t, lds);
        g.sync();
        ph_agg(p, p.x8g, p.x8d, p.mdh, p.mgh, bx, t);
        g.sync();
        ph_gemm(p, bx, t, 1);
        g.sync();
        ph_agg(p, p.g18, p.d18, p.mdh, p.mgh, bx, t);
        g.sync();
        ph_gemm(p, bx, t, 2);
        return;
    }
    switch (phase) {
        case 0: ph_prep(p, bx, t); ph_hist(p, bx, t, lds); break;
        case 1: ph_colscan(p, bx, t, lds); break;
        case 2: ph_scan1(p, bx, t, (int*)lds); break;
        case 3: ph_scan2(p, bx, t); break;
        case 4: ph_fill(p, bx, t, lds); break;
        case 5: ph_agg(p, p.x8g, p.x8d, p.mdh, p.mgh, bx, t); break;
        case 6: ph_gemm(p, bx, t, 1); break;
        case 7: ph_agg(p, p.g18, p.d18, p.mdh, p.mgh, bx, t); break;
        case 8: ph_gemm(p, bx, t, 2); break;
    }
}

extern "C" void kernel_launch(void* const* d_in, const int* in_sizes, int n_in,
                              void* d_out, int out_size, void* d_ws, size_t ws_size,
                              hipStream_t stream) {
    char* ws = (char*)d_ws;
    P p;
    p.xd  = (const float*)d_in[0];
    p.xg  = (const float*)d_in[1];
    p.src = (const int*)d_in[2];
    p.dst = (const int*)d_in[3];
    p.w[0] = (const float*)d_in[4];   // w1_dg_l
    p.w[1] = (const float*)d_in[6];   // w1_dg_r
    p.w[2] = (const float*)d_in[7];   // w1_gd_l
    p.w[3] = (const float*)d_in[9];   // w1_gd_r
    p.w[4] = (const float*)d_in[10];  // w2_dg_l
    p.w[5] = (const float*)d_in[12];  // w2_dg_r
    p.w[6] = (const float*)d_in[13];  // w2_gd_l
    p.w[7] = (const float*)d_in[15];  // w2_gd_r
    p.b1dg = (const float*)d_in[5];
    p.b1gd = (const float*)d_in[8];
    p.b2dg = (const float*)d_in[11];
    p.b2gd = (const float*)d_in[14];
    p.cnt   = (int*)(ws + OFF_CNT);
    p.row   = (int*)(ws + OFF_ROW);
    p.bsum  = (int*)(ws + OFF_BSUM);
    p.partD = (unsigned short*)(ws + OFF_PARTD);
    p.partG = (unsigned short*)(ws + OFF_PARTG);
    p.col   = (unsigned short*)(ws + OFF_COL);
    p.wsw   = (_Float16*)(ws + OFF_WSW);
    p.xdh   = (__half*)(ws + OFF_XDH);
    p.xgh   = (__half*)(ws + OFF_XGH);
    p.x8d   = (unsigned char*)(ws + OFF_X8D);
    p.x8g   = (unsigned char*)(ws + OFF_X8G);
    p.mdh   = (__half*)(ws + OFF_MDH);
    p.mgh   = (__half*)(ws + OFF_MGH);
    p.d1h   = (__half*)(ws + OFF_D1H);
    p.g1h   = (__half*)(ws + OFF_G1H);
    p.d18   = (unsigned char*)(ws + OFF_D18);
    p.g18   = (unsigned char*)(ws + OFF_G18);
    p.outd  = (float*)d_out;
    p.outg  = (float*)d_out + (size_t)ND * 128;
    p.E     = in_sizes[2];            // 1,000,000

    int ph = -1;
    void* args[] = {&p, &ph};
    hipError_t err = hipLaunchCooperativeKernel((void*)mega, dim3(GRID), dim3(256),
                                                args, 0, stream);
    if (err != hipSuccess) {
        // fallback: same phases as 9 plain dispatches (boundaries act as barriers)
        for (int k = 0; k < 9; ++k)
            mega<<<GRID, 256, 0, stream>>>(p, k);
    }
}

// Round 10
// 372.744 us; speedup vs baseline: 2.8558x; 2.8558x over previous
//
#include <hip/hip_runtime.h>
#include <hip/hip_fp16.h>

#define ND 25000
#define NG 20000
#define NTOT (ND + NG)      // 45000
#define NBLK 128            // hist/fill slices PER NODE TYPE (2*NBLK = 256 blocks)
#define PREPB 1024          // prep blocks appended after the 256 hist blocks
#define LDP 136             // LDS mean-row stride (f16 elems): 136*2=272 B -> 2-way bank alias only

typedef _Float16 half8 __attribute__((ext_vector_type(8)));
typedef float f32x4 __attribute__((ext_vector_type(4)));
typedef float f32x2 __attribute__((ext_vector_type(2)));

// ---- workspace layout (bytes), 256B-aligned ----
#define OFF_CNT    0ull           // NTOT int (180000)
#define OFF_ROW    180224ull      // NTOT+1 int
#define OFF_PARTD  360704ull      // NBLK*ND u16 (6,400,000)
#define OFF_PARTG  6760704ull     // NBLK*NG u16 (5,120,000)
#define OFF_COL    11880704ull    // 2*NE u16 (4,000,000)
#define OFF_WSW    15880704ull    // 8*128*128 half (262,144)
#define OFF_XDH    16142848ull    // ND*128 half (6,400,000)
#define OFF_XGH    22542848ull    // NG*128 half (5,120,000)
#define OFF_X8D    27662848ull    // ND*128 fp8 (3,200,000)
#define OFF_X8G    30862848ull    // NG*128 fp8 (2,560,000)
#define OFF_D1H    33422848ull    // ND*128 half (6,400,000)
#define OFF_G1H    39822848ull    // NG*128 half (5,120,000)
#define OFF_D18    44942848ull    // ND*128 fp8 (3,200,000)
#define OFF_G18    48142848ull    // NG*128 fp8 (2,560,000)  (end ~50.7 MB)

struct WPtrs { const float* w[8]; };

// ---------------- dispatch 1: hist (blocks 0..2*NBLK-1) + prep/convert/swizzle (rest) ------------
__global__ __launch_bounds__(256) void prep_hist(const float* __restrict__ xd,
                                                 const float* __restrict__ xg,
                                                 __half* __restrict__ ydh,
                                                 __half* __restrict__ ygh,
                                                 unsigned char* __restrict__ y8d,
                                                 unsigned char* __restrict__ y8g,
                                                 WPtrs wp, _Float16* __restrict__ wsw,
                                                 const int* __restrict__ src,
                                                 const int* __restrict__ dst,
                                                 unsigned short* __restrict__ partD,
                                                 unsigned short* __restrict__ partG, int E) {
    __shared__ unsigned int h[12544];     // 50176 B
    int bx = blockIdx.x, t = threadIdx.x;
    if (bx < 2 * NBLK) {                  // ---- privatized histogram ----
        bool isD = bx < NBLK;
        int bb = isD ? bx : bx - NBLK;
        const int* key = isD ? src : dst;
        int nw = isD ? (ND / 2) : (NG / 2);
        for (int i = t; i < nw; i += 256) h[i] = 0;
        __syncthreads();
        int e0 = (int)(((long long)E * bb) / NBLK);
        int e1 = (int)(((long long)E * (bb + 1)) / NBLK);
        for (int e = e0 + t; e < e1; e += 256) {
            int k = key[e];
            atomicAdd(&h[k >> 1], 1u << ((k & 1) * 16));
        }
        __syncthreads();
        unsigned int* po = (unsigned int*)((isD ? partD : partG) + (size_t)bb * (isD ? ND : NG));
        for (int i = t; i < nw; i += 256) po[i] = h[i];
        return;
    }
    int pb = bx - 2 * NBLK;               // ---- prep: convert + swizzle ----
    if (pb < 8) {   // W swizzle: slot=(ntile*4+kc)*64+lane; elem j = W[kc*32+(lane>>4)*8+j][ntile*16+(lane&15)]
        const float* W = wp.w[pb];
        _Float16* o = wsw + (size_t)pb * 16384;
        for (int rep = 0; rep < 8; ++rep) {
            int slot = rep * 256 + t;
            int lane = slot & 63, grp = slot >> 6;
            int kc = grp & 3, ntile = grp >> 2;
            int nn = ntile * 16 + (lane & 15);
            int kb = kc * 32 + (lane >> 4) * 8;
            half8 v;
#pragma unroll
            for (int j = 0; j < 8; ++j) v[j] = (_Float16)W[(size_t)(kb + j) * 128 + nn];
            *(half8*)(o + (size_t)slot * 8) = v;
        }
    }
    const int ndq = ND * 32;
    const int tot = ndq + NG * 32;
    for (int i = pb * 256 + t; i < tot; i += PREPB * 256) {
        const float* x;
        __half* y;
        unsigned char* y8;
        int idx;
        if (i < ndq) { x = xd; y = ydh; y8 = y8d; idx = i; }
        else         { x = xg; y = ygh; y8 = y8g; idx = i - ndq; }
        float4 v = ((const float4*)x)[idx];
        ((__half2*)y)[idx * 2 + 0] = __floats2half2_rn(v.x, v.y);
        ((__half2*)y)[idx * 2 + 1] = __floats2half2_rn(v.z, v.w);
        int p8 = __builtin_amdgcn_cvt_pk_fp8_f32(v.x, v.y, 0, false);
        p8 = __builtin_amdgcn_cvt_pk_fp8_f32(v.z, v.w, p8, true);
        ((int*)y8)[idx] = p8;
    }
}

// ---------------- dispatch 2: column scan over partials ------------------------------------------
__global__ __launch_bounds__(256) void colscan2(unsigned short* __restrict__ partD,
                                                unsigned short* __restrict__ partG,
                                                int* __restrict__ cnt) {
    int k = blockIdx.x * 256 + threadIdx.x;
    if (k >= NTOT) return;
    unsigned short* part;
    int nb, kk;
    if (k < ND) { part = partD; nb = ND; kk = k; }
    else        { part = partG; nb = NG; kk = k - ND; }
    int run = 0;
#pragma unroll 8
    for (int b = 0; b < NBLK; ++b) {
        size_t idx = (size_t)b * nb + kk;
        int v = part[idx];
        part[idx] = (unsigned short)run;
        run += v;
    }
    cnt[k] = run;
}

// ---------------- dispatch 3: single-block exclusive scan of cnt -> row --------------------------
__global__ __launch_bounds__(1024) void scanrow(const int* __restrict__ cnt,
                                                int* __restrict__ row, int total) {
    __shared__ int sd[1024];
    int t = threadIdx.x;
    const int C = 44;                       // 44*1024 = 45056 >= NTOT
    int base = t * C;
    int sum = 0;
    for (int j = 0; j < C; ++j) {
        int idx = base + j;
        if (idx < NTOT) sum += cnt[idx];
    }
    sd[t] = sum;
    __syncthreads();
    for (int off = 1; off < 1024; off <<= 1) {
        int x = (t >= off) ? sd[t - off] : 0;
        __syncthreads();
        sd[t] += x;
        __syncthreads();
    }
    int run = sd[t] - sum;                  // exclusive prefix for this thread's chunk
    for (int j = 0; j < C; ++j) {
        int idx = base + j;
        if (idx < NTOT) {
            row[idx] = run;
            run += cnt[idx];
        }
    }
    if (t == 1023) row[NTOT] = total;
}

// ---------------- dispatch 4: atomic-free CSR fill -----------------------------------------------
__global__ __launch_bounds__(256) void fill2(const int* __restrict__ src,
                                             const int* __restrict__ dst,
                                             const int* __restrict__ row,
                                             const unsigned short* __restrict__ partD,
                                             const unsigned short* __restrict__ partG,
                                             unsigned short* __restrict__ col, int E) {
    __shared__ unsigned int h[12544];
    int t = threadIdx.x, b = blockIdx.x;
    bool isD = b < NBLK;
    int bb = isD ? b : b - NBLK;
    const int* key = isD ? src : dst;
    const int* val = isD ? dst : src;
    const int* rowp = isD ? row : row + ND;
    int nw = isD ? (ND / 2) : (NG / 2);
    const unsigned int* pi =
        (const unsigned int*)((isD ? partD : partG) + (size_t)bb * (isD ? ND : NG));
    for (int i = t; i < nw; i += 256) h[i] = pi[i];
    __syncthreads();
    int e0 = (int)(((long long)E * bb) / NBLK);
    int e1 = (int)(((long long)E * (bb + 1)) / NBLK);
    for (int e = e0 + t; e < e1; e += 256) {
        int k = key[e];
        int v = val[e];
        unsigned int old = atomicAdd(&h[k >> 1], 1u << ((k & 1) * 16));
        int rank = (old >> ((k & 1) * 16)) & 0xffff;
        col[rowp[k] + rank] = (unsigned short)v;
    }
}

// ---------------- dispatches 5/6: fused aggregation + dual MFMA GEMM -----------------------------
// Block = 4 waves x 16 nodes = 64 rows. Each wave: (a) fp8 gather-mean per node (8 lanes/row,
// 8 rows in flight) -> f16 row into wave-private LDS tile (stride LDP); (b) dual GEMM
// Y = mean@W1 + A2@W2 + b with A1 frags from LDS, A2 from global. No barriers (wave-private LDS).
struct AG {
    const unsigned char *Xg8, *Xd8;       // gather sources (opposite type, fp8)
    const __half *A2d, *A2g;              // self features f16
    const _Float16 *W1d, *W2d, *W1g, *W2g;
    const float *biasd, *biasg;
    const int* row;
    const unsigned short* col;
    __half *Yhd, *Yhg;                    // layer1 f16 out
    unsigned char *Y8d, *Y8g;             // layer1 fp8 shadow
    float *Yfd, *Yfg;                     // layer2 f32 out
};
__global__ __launch_bounds__(256) void aggemm(AG p, int layer) {
    __shared__ _Float16 am[4 * 16 * LDP];      // 17408 B
    const int nblkD = (ND + 63) / 64;          // 391
    int bx = blockIdx.x, t = threadIdx.x;
    bool isD = bx < nblkD;
    int n = isD ? ND : NG, b0 = isD ? bx : bx - nblkD;
    const unsigned char* X8 = isD ? p.Xg8 : p.Xd8;
    const __half* A2 = isD ? p.A2d : p.A2g;
    const _Float16* W1 = isD ? p.W1d : p.W1g;
    const _Float16* W2 = isD ? p.W2d : p.W2g;
    const float* bias = isD ? p.biasd : p.biasg;
    const int* rowp = isD ? p.row : p.row + ND;
    int wave = t >> 6, lane = t & 63;
    int row0 = b0 * 64 + wave * 16;
    if (row0 >= n) return;
    int g = lane >> 3, f = lane & 7;
    _Float16* wbase = am + wave * 16 * LDP;

    // ---- phase A: aggregate 16 nodes into LDS ----
    for (int i = 0; i < 16; ++i) {
        int node = row0 + i;
        int b = 0, e = 0;
        if (node < n) { b = rowp[node]; e = rowp[node + 1]; }
        float acc[16];
#pragma unroll
        for (int k = 0; k < 16; ++k) acc[k] = 0.f;
        int j = b + g;
        for (; j + 8 < e; j += 16) {
            int c0 = p.col[j], c1 = p.col[j + 8];
            int4 w0 = *(const int4*)(X8 + (size_t)c0 * 128 + f * 16);
            int4 w1 = *(const int4*)(X8 + (size_t)c1 * 128 + f * 16);
            const int* wa = (const int*)&w0;
            const int* wb = (const int*)&w1;
#pragma unroll
            for (int q = 0; q < 4; ++q) {
                f32x2 l0 = __builtin_amdgcn_cvt_pk_f32_fp8(wa[q], false);
                f32x2 h0 = __builtin_amdgcn_cvt_pk_f32_fp8(wa[q], true);
                f32x2 l1 = __builtin_amdgcn_cvt_pk_f32_fp8(wb[q], false);
                f32x2 h1 = __builtin_amdgcn_cvt_pk_f32_fp8(wb[q], true);
                acc[q * 4 + 0] += l0[0] + l1[0];
                acc[q * 4 + 1] += l0[1] + l1[1];
                acc[q * 4 + 2] += h0[0] + h1[0];
                acc[q * 4 + 3] += h0[1] + h1[1];
            }
        }
        if (j < e) {
            int c = p.col[j];
            int4 w = *(const int4*)(X8 + (size_t)c * 128 + f * 16);
            const int* wa = (const int*)&w;
#pragma unroll
            for (int q = 0; q < 4; ++q) {
                f32x2 l = __builtin_amdgcn_cvt_pk_f32_fp8(wa[q], false);
                f32x2 h = __builtin_amdgcn_cvt_pk_f32_fp8(wa[q], true);
                acc[q * 4 + 0] += l[0];
                acc[q * 4 + 1] += l[1];
                acc[q * 4 + 2] += h[0];
                acc[q * 4 + 3] += h[1];
            }
        }
#pragma unroll
        for (int k = 0; k < 16; ++k) {
            acc[k] += __shfl_xor(acc[k], 8, 64);
            acc[k] += __shfl_xor(acc[k], 16, 64);
            acc[k] += __shfl_xor(acc[k], 32, 64);
        }
        if (g == 0) {
            int deg = e - b;
            float r = 1.0f / (float)(deg > 0 ? deg : 1);
            half8 o0, o1;
#pragma unroll
            for (int k = 0; k < 8; ++k) o0[k] = (_Float16)(acc[k] * r);
#pragma unroll
            for (int k = 0; k < 8; ++k) o1[k] = (_Float16)(acc[8 + k] * r);
            _Float16* op = wbase + i * LDP + f * 16;
            *(half8*)op = o0;
            *(half8*)(op + 8) = o1;
        }
    }

    // ---- phase B: dual GEMM (same wave reads its own LDS tile; compiler emits lgkmcnt waits) ----
    int m = lane & 15, quad = lane >> 4;
    int arow = row0 + m;
    if (arow >= n) arow = n - 1;
    const _Float16* a2p = (const _Float16*)A2 + (size_t)arow * 128 + quad * 8;
    half8 a1[4], a2[4];
#pragma unroll
    for (int kc = 0; kc < 4; ++kc) {
        a1[kc] = *(const half8*)(wbase + m * LDP + kc * 32 + quad * 8);
        a2[kc] = *(const half8*)(a2p + kc * 32);
    }
#pragma unroll
    for (int ntile = 0; ntile < 8; ++ntile) {
        f32x4 acc = {0.f, 0.f, 0.f, 0.f};
#pragma unroll
        for (int kc = 0; kc < 4; ++kc) {
            half8 b1 = *(const half8*)(W1 + (size_t)((ntile * 4 + kc) * 64 + lane) * 8);
            acc = __builtin_amdgcn_mfma_f32_16x16x32_f16(a1[kc], b1, acc, 0, 0, 0);
            half8 b2 = *(const half8*)(W2 + (size_t)((ntile * 4 + kc) * 64 + lane) * 8);
            acc = __builtin_amdgcn_mfma_f32_16x16x32_f16(a2[kc], b2, acc, 0, 0, 0);
        }
        int colx = ntile * 16 + m;
        float bb = bias[colx];
        float* Yf = isD ? p.Yfd : p.Yfg;
        __half* Yh = isD ? p.Yhd : p.Yhg;
        unsigned char* Y8 = isD ? p.Y8d : p.Y8g;
#pragma unroll
        for (int r = 0; r < 4; ++r) {
            int rr = row0 + quad * 4 + r;
            if (rr < n) {
                float v = acc[r] + bb;
                if (layer == 2) {
                    Yf[(size_t)rr * 128 + colx] = v;
                } else {
                    Yh[(size_t)rr * 128 + colx] = __float2half(v);
                    int p8 = __builtin_amdgcn_cvt_pk_fp8_f32(v, v, 0, false);
                    Y8[(size_t)rr * 128 + colx] = (unsigned char)(p8 & 0xff);
                }
            }
        }
    }
}

extern "C" void kernel_launch(void* const* d_in, const int* in_sizes, int n_in,
                              void* d_out, int out_size, void* d_ws, size_t ws_size,
                              hipStream_t stream) {
    const float* x_d = (const float*)d_in[0];
    const float* x_g = (const float*)d_in[1];
    const int*   src = (const int*)d_in[2];
    const int*   dst = (const int*)d_in[3];
    float* out = (float*)d_out;

    char* ws = (char*)d_ws;
    int*            cnt   = (int*)(ws + OFF_CNT);
    int*            row   = (int*)(ws + OFF_ROW);
    unsigned short* partD = (unsigned short*)(ws + OFF_PARTD);
    unsigned short* partG = (unsigned short*)(ws + OFF_PARTG);
    unsigned short* col   = (unsigned short*)(ws + OFF_COL);
    _Float16*       wsw   = (_Float16*)(ws + OFF_WSW);
    __half*         xd_h  = (__half*)(ws + OFF_XDH);
    __half*         xg_h  = (__half*)(ws + OFF_XGH);
    unsigned char*  x8d   = (unsigned char*)(ws + OFF_X8D);
    unsigned char*  x8g   = (unsigned char*)(ws + OFF_X8G);
    __half*         d1_h  = (__half*)(ws + OFF_D1H);
    __half*         g1_h  = (__half*)(ws + OFF_G1H);
    unsigned char*  d1_8  = (unsigned char*)(ws + OFF_D18);
    unsigned char*  g1_8  = (unsigned char*)(ws + OFF_G18);

    const int E = in_sizes[2];              // 1,000,000
    const int nblkD = (ND + 63) / 64;       // 391
    const int nblkG = (NG + 63) / 64;       // 313

    WPtrs wp;
    wp.w[0] = (const float*)d_in[4];   // w1_dg_l
    wp.w[1] = (const float*)d_in[6];   // w1_dg_r
    wp.w[2] = (const float*)d_in[7];   // w1_gd_l
    wp.w[3] = (const float*)d_in[9];   // w1_gd_r
    wp.w[4] = (const float*)d_in[10];  // w2_dg_l
    wp.w[5] = (const float*)d_in[12];  // w2_dg_r
    wp.w[6] = (const float*)d_in[13];  // w2_gd_l
    wp.w[7] = (const float*)d_in[15];  // w2_gd_r
    const float* b1_dg = (const float*)d_in[5];
    const float* b1_gd = (const float*)d_in[8];
    const float* b2_dg = (const float*)d_in[11];
    const float* b2_gd = (const float*)d_in[14];

    // 1. hist + prep (independent, disjoint block ranges)
    prep_hist<<<2 * NBLK + PREPB, 256, 0, stream>>>(x_d, x_g, xd_h, xg_h, x8d, x8g,
                                                    wp, wsw, src, dst, partD, partG, E);
    // 2-3. partial scan -> rowptr
    colscan2<<<(NTOT + 255) / 256, 256, 0, stream>>>(partD, partG, cnt);
    scanrow<<<1, 1024, 0, stream>>>(cnt, row, 2 * E);
    // 4. CSR fill
    fill2<<<2 * NBLK, 256, 0, stream>>>(src, dst, row, partD, partG, col, E);

    // 5. layer 1: fused agg + GEMM (f16 + fp8 shadow out)
    AG a1;
    a1.Xg8 = x8g; a1.Xd8 = x8d;
    a1.A2d = xd_h; a1.A2g = xg_h;
    a1.W1d = wsw + 2 * 16384; a1.W2d = wsw + 3 * 16384;   // w1_gd_l, w1_gd_r
    a1.W1g = wsw + 0 * 16384; a1.W2g = wsw + 1 * 16384;   // w1_dg_l, w1_dg_r
    a1.biasd = b1_gd; a1.biasg = b1_dg;
    a1.row = row; a1.col = col;
    a1.Yhd = d1_h; a1.Yhg = g1_h; a1.Y8d = d1_8; a1.Y8g = g1_8;
    a1.Yfd = nullptr; a1.Yfg = nullptr;
    aggemm<<<nblkD + nblkG, 256, 0, stream>>>(a1, 1);

    // 6. layer 2: fused agg + GEMM (f32 out)
    AG a2;
    a2.Xg8 = g1_8; a2.Xd8 = d1_8;
    a2.A2d = d1_h; a2.A2g = g1_h;
    a2.W1d = wsw + 6 * 16384; a2.W2d = wsw + 7 * 16384;   // w2_gd_l, w2_gd_r
    a2.W1g = wsw + 4 * 16384; a2.W2g = wsw + 5 * 16384;   // w2_dg_l, w2_dg_r
    a2.biasd = b2_gd; a2.biasg = b2_dg;
    a2.row = row; a2.col = col;
    a2.Yhd = nullptr; a2.Yhg = nullptr; a2.Y8d = nullptr; a2.Y8g = nullptr;
    a2.Yfd = out; a2.Yfg = out + (size_t)ND * 128;
    aggemm<<<nblkD + nblkG, 256, 0, stream>>>(a2, 2);
}

// Round 11
// 251.696 us; speedup vs baseline: 4.2292x; 1.4809x over previous
//
#include <hip/hip_runtime.h>
#include <hip/hip_fp16.h>

#define ND 25000
#define NG 20000
#define NTOT (ND + NG)      // 45000
#define NSCAN_BLOCKS 44     // ceil(45000/1024)
#define NBLK 128            // hist/fill slices PER NODE TYPE (2*NBLK = 256 blocks)
#define PREPB 1024          // prep blocks appended after the 256 hist blocks

typedef _Float16 half8 __attribute__((ext_vector_type(8)));
typedef float f32x4 __attribute__((ext_vector_type(4)));
typedef float f32x2 __attribute__((ext_vector_type(2)));

// ---- workspace layout (bytes), 256B-aligned ----
#define OFF_CNT    0ull           // NTOT int (180000)
#define OFF_ROW    180224ull      // NTOT+1 int
#define OFF_BSUM   360448ull      // 44 int
#define OFF_PARTD  360704ull      // NBLK*ND u16 (6,400,000)
#define OFF_PARTG  6760704ull     // NBLK*NG u16 (5,120,000)
#define OFF_COL    11880704ull    // 2*NE u16 (4,000,000)
#define OFF_WSW    15880704ull    // 8*128*128 half (262,144)
#define OFF_XDH    16142848ull    // ND*128 half (6,400,000)
#define OFF_XGH    22542848ull    // NG*128 half (5,120,000)
#define OFF_X8D    27662848ull    // ND*128 fp8 (3,200,000)
#define OFF_X8G    30862848ull    // NG*128 fp8 (2,560,000)
#define OFF_MDH    33422848ull    // ND*128 half (6,400,000)
#define OFF_MGH    39822848ull    // NG*128 half (5,120,000)
#define OFF_D1H    44942848ull    // ND*128 half (6,400,000)
#define OFF_G1H    51342848ull    // NG*128 half (5,120,000)
#define OFF_D18    56462848ull    // ND*128 fp8 (3,200,000)
#define OFF_G18    59662848ull    // NG*128 fp8 (2,560,000)  (end ~62.2 MB)

struct WPtrs { const float* w[8]; };

// ---------------- dispatch 1: hist (blocks 0..2*NBLK-1) + prep/convert/swizzle (rest) ------------
__global__ __launch_bounds__(256) void prep_hist(const float* __restrict__ xd,
                                                 const float* __restrict__ xg,
                                                 __half* __restrict__ ydh,
                                                 __half* __restrict__ ygh,
                                                 unsigned char* __restrict__ y8d,
                                                 unsigned char* __restrict__ y8g,
                                                 WPtrs wp, _Float16* __restrict__ wsw,
                                                 const int* __restrict__ src,
                                                 const int* __restrict__ dst,
                                                 unsigned short* __restrict__ partD,
                                                 unsigned short* __restrict__ partG, int E) {
    __shared__ unsigned int h[12544];     // 50176 B
    int bx = blockIdx.x, t = threadIdx.x;
    if (bx < 2 * NBLK) {                  // ---- privatized histogram ----
        bool isD = bx < NBLK;
        int bb = isD ? bx : bx - NBLK;
        const int* key = isD ? src : dst;
        int nw = isD ? (ND / 2) : (NG / 2);
        for (int i = t; i < nw; i += 256) h[i] = 0;
        __syncthreads();
        int e0 = (int)(((long long)E * bb) / NBLK);
        int e1 = (int)(((long long)E * (bb + 1)) / NBLK);
        for (int e = e0 + t; e < e1; e += 256) {
            int k = key[e];
            atomicAdd(&h[k >> 1], 1u << ((k & 1) * 16));
        }
        __syncthreads();
        unsigned int* po = (unsigned int*)((isD ? partD : partG) + (size_t)bb * (isD ? ND : NG));
        for (int i = t; i < nw; i += 256) po[i] = h[i];
        return;
    }
    int pb = bx - 2 * NBLK;               // ---- prep: convert + swizzle ----
    if (pb < 8) {   // W swizzle: slot=(ntile*4+kc)*64+lane; elem j = W[kc*32+(lane>>4)*8+j][ntile*16+(lane&15)]
        const float* W = wp.w[pb];
        _Float16* o = wsw + (size_t)pb * 16384;
        for (int rep = 0; rep < 8; ++rep) {
            int slot = rep * 256 + t;
            int lane = slot & 63, grp = slot >> 6;
            int kc = grp & 3, ntile = grp >> 2;
            int nn = ntile * 16 + (lane & 15);
            int kb = kc * 32 + (lane >> 4) * 8;
            half8 v;
#pragma unroll
            for (int j = 0; j < 8; ++j) v[j] = (_Float16)W[(size_t)(kb + j) * 128 + nn];
            *(half8*)(o + (size_t)slot * 8) = v;
        }
    }
    const int ndq = ND * 32;
    const int tot = ndq + NG * 32;
    for (int i = pb * 256 + t; i < tot; i += PREPB * 256) {
        const float* x;
        __half* y;
        unsigned char* y8;
        int idx;
        if (i < ndq) { x = xd; y = ydh; y8 = y8d; idx = i; }
        else         { x = xg; y = ygh; y8 = y8g; idx = i - ndq; }
        float4 v = ((const float4*)x)[idx];
        ((__half2*)y)[idx * 2 + 0] = __floats2half2_rn(v.x, v.y);
        ((__half2*)y)[idx * 2 + 1] = __floats2half2_rn(v.z, v.w);
        int p8 = __builtin_amdgcn_cvt_pk_fp8_f32(v.x, v.y, 0, false);
        p8 = __builtin_amdgcn_cvt_pk_fp8_f32(v.z, v.w, p8, true);
        ((int*)y8)[idx] = p8;
    }
}

// ---------------- dispatch 2: column scan over partials ------------------------------------------
__global__ __launch_bounds__(256) void colscan2(unsigned short* __restrict__ partD,
                                                unsigned short* __restrict__ partG,
                                                int* __restrict__ cnt) {
    int k = blockIdx.x * 256 + threadIdx.x;
    if (k >= NTOT) return;
    unsigned short* part;
    int nb, kk;
    if (k < ND) { part = partD; nb = ND; kk = k; }
    else        { part = partG; nb = NG; kk = k - ND; }
    int run = 0;
#pragma unroll 8
    for (int b = 0; b < NBLK; ++b) {
        size_t idx = (size_t)b * nb + kk;
        int v = part[idx];
        part[idx] = (unsigned short)run;
        run += v;
    }
    cnt[k] = run;
}

// ---------------- dispatch 3: row-ptr scan pass 1 (44 blocks x 1024 elems) -----------------------
__global__ __launch_bounds__(256) void scan1(const int* __restrict__ cnt,
                                             int* __restrict__ row,
                                             int* __restrict__ bsum, int N) {
    __shared__ int sd[256];
    int t = threadIdx.x;
    int base = blockIdx.x * 1024 + t * 4;
    int v[4];
#pragma unroll
    for (int j = 0; j < 4; ++j) {
        int idx = base + j;
        v[j] = (idx < N) ? cnt[idx] : 0;
    }
    int tsum = v[0] + v[1] + v[2] + v[3];
    sd[t] = tsum;
    __syncthreads();
    for (int off = 1; off < 256; off <<= 1) {
        int x = (t >= off) ? sd[t - off] : 0;
        __syncthreads();
        sd[t] += x;
        __syncthreads();
    }
    int run = sd[t] - tsum;
#pragma unroll
    for (int j = 0; j < 4; ++j) {
        int idx = base + j;
        if (idx < N) row[idx] = run;
        run += v[j];
    }
    if (t == 255) bsum[blockIdx.x] = sd[255];
}

// ---------------- dispatch 4: row-ptr scan pass 2 ------------------------------------------------
__global__ __launch_bounds__(256) void scan2(int* __restrict__ row,
                                             const int* __restrict__ bsum,
                                             int N, int total) {
    int off = 0;
    for (int b2 = 0; b2 < (int)blockIdx.x; ++b2) off += bsum[b2];
    int t = threadIdx.x;
    int base = blockIdx.x * 1024 + t * 4;
#pragma unroll
    for (int j = 0; j < 4; ++j) {
        int idx = base + j;
        if (idx < N) row[idx] += off;
    }
    if (blockIdx.x == 0 && t == 0) row[N] = total;
}

// ---------------- dispatch 5: atomic-free CSR fill -----------------------------------------------
__global__ __launch_bounds__(256) void fill2(const int* __restrict__ src,
                                             const int* __restrict__ dst,
                                             const int* __restrict__ row,
                                             const unsigned short* __restrict__ partD,
                                             const unsigned short* __restrict__ partG,
                                             unsigned short* __restrict__ col, int E) {
    __shared__ unsigned int h[12544];
    int t = threadIdx.x, b = blockIdx.x;
    bool isD = b < NBLK;
    int bb = isD ? b : b - NBLK;
    const int* key = isD ? src : dst;
    const int* val = isD ? dst : src;
    const int* rowp = isD ? row : row + ND;
    int nw = isD ? (ND / 2) : (NG / 2);
    const unsigned int* pi =
        (const unsigned int*)((isD ? partD : partG) + (size_t)bb * (isD ? ND : NG));
    for (int i = t; i < nw; i += 256) h[i] = pi[i];
    __syncthreads();
    int e0 = (int)(((long long)E * bb) / NBLK);
    int e1 = (int)(((long long)E * (bb + 1)) / NBLK);
    for (int e = e0 + t; e < e1; e += 256) {
        int k = key[e];
        int v = val[e];
        unsigned int old = atomicAdd(&h[k >> 1], 1u << ((k & 1) * 16));
        int rank = (old >> ((k & 1) * 16)) & 0xffff;
        col[rowp[k] + rank] = (unsigned short)v;
    }
}

// ---------------- dispatches 6/8: fp8 mean aggregation (one wave per node) -----------------------
// 8 lanes per neighbor row (16 B/lane), 8 rows in flight per wave load, x2 unroll; f16 out.
__global__ __launch_bounds__(256) void agg8m(const unsigned char* __restrict__ Xg,
                                             const unsigned char* __restrict__ Xd,
                                             const int* __restrict__ row,
                                             const unsigned short* __restrict__ col,
                                             __half* __restrict__ outd,
                                             __half* __restrict__ outg) {
    int wid = threadIdx.x >> 6, lane = threadIdx.x & 63;
    int node = blockIdx.x * 4 + wid;
    if (node >= NTOT) return;
    const unsigned char* X;
    _Float16* out;
    int nloc;
    if (node < ND) { X = Xg; out = (_Float16*)outd; nloc = node; }
    else           { X = Xd; out = (_Float16*)outg; nloc = node - ND; }
    int b = row[node], e = row[node + 1];
    int g = lane >> 3, f = lane & 7;
    float acc[16];
#pragma unroll
    for (int k = 0; k < 16; ++k) acc[k] = 0.f;
    int j = b + g;
    for (; j + 8 < e; j += 16) {
        int c0 = col[j], c1 = col[j + 8];
        int4 w0 = *(const int4*)(X + (size_t)c0 * 128 + f * 16);
        int4 w1 = *(const int4*)(X + (size_t)c1 * 128 + f * 16);
        const int* wa = (const int*)&w0;
        const int* wb = (const int*)&w1;
#pragma unroll
        for (int q = 0; q < 4; ++q) {
            f32x2 l0 = __builtin_amdgcn_cvt_pk_f32_fp8(wa[q], false);
            f32x2 h0 = __builtin_amdgcn_cvt_pk_f32_fp8(wa[q], true);
            f32x2 l1 = __builtin_amdgcn_cvt_pk_f32_fp8(wb[q], false);
            f32x2 h1 = __builtin_amdgcn_cvt_pk_f32_fp8(wb[q], true);
            acc[q * 4 + 0] += l0[0] + l1[0];
            acc[q * 4 + 1] += l0[1] + l1[1];
            acc[q * 4 + 2] += h0[0] + h1[0];
            acc[q * 4 + 3] += h0[1] + h1[1];
        }
    }
    if (j < e) {
        int c = col[j];
        int4 w = *(const int4*)(X + (size_t)c * 128 + f * 16);
        const int* wa = (const int*)&w;
#pragma unroll
        for (int q = 0; q < 4; ++q) {
            f32x2 l = __builtin_amdgcn_cvt_pk_f32_fp8(wa[q], false);
            f32x2 h = __builtin_amdgcn_cvt_pk_f32_fp8(wa[q], true);
            acc[q * 4 + 0] += l[0];
            acc[q * 4 + 1] += l[1];
            acc[q * 4 + 2] += h[0];
            acc[q * 4 + 3] += h[1];
        }
    }
#pragma unroll
    for (int k = 0; k < 16; ++k) {
        acc[k] += __shfl_xor(acc[k], 8, 64);
        acc[k] += __shfl_xor(acc[k], 16, 64);
        acc[k] += __shfl_xor(acc[k], 32, 64);
    }
    if (g == 0) {
        int deg = e - b;
        float r = 1.0f / (float)(deg > 0 ? deg : 1);
        half8 o0, o1;
#pragma unroll
        for (int k = 0; k < 8; ++k) o0[k] = (_Float16)(acc[k] * r);
#pragma unroll
        for (int k = 0; k < 8; ++k) o1[k] = (_Float16)(acc[8 + k] * r);
        _Float16* op = out + (size_t)nloc * 128 + f * 16;
        *(half8*)op = o0;
        *(half8*)(op + 8) = o1;
    }
}

// ---------------- dispatches 7/9: merged MFMA dual GEMM ------------------------------------------
struct GemmDual {
    const __half *A1d, *A2d, *A1g, *A2g;
    const _Float16 *W1d, *W2d, *W1g, *W2g;
    const float *biasd, *biasg;
    float *Yfd, *Yfg;
    __half *Yhd, *Yhg;
    unsigned char *Y8d, *Y8g;
};
__global__ __launch_bounds__(256) void gemm2(GemmDual p, int nblkD, int layer) {
    int bx = blockIdx.x;
    bool isD = bx < nblkD;
    const __half* A1 = isD ? p.A1d : p.A1g;
    const __half* A2 = isD ? p.A2d : p.A2g;
    const _Float16* W1 = isD ? p.W1d : p.W1g;
    const _Float16* W2 = isD ? p.W2d : p.W2g;
    const float* bias = isD ? p.biasd : p.biasg;
    float* Yf = isD ? p.Yfd : p.Yfg;
    __half* Yh = isD ? p.Yhd : p.Yhg;
    unsigned char* Y8 = isD ? p.Y8d : p.Y8g;
    int n = isD ? ND : NG, b0 = isD ? bx : bx - nblkD;
    int t = threadIdx.x;
    int wave = t >> 6, lane = t & 63;
    int row0 = b0 * 64 + wave * 16;
    if (row0 >= n) return;
    int m = lane & 15, quad = lane >> 4;
    int arow = row0 + m;
    if (arow >= n) arow = n - 1;
    const _Float16* a1p = (const _Float16*)A1 + (size_t)arow * 128 + quad * 8;
    const _Float16* a2p = (const _Float16*)A2 + (size_t)arow * 128 + quad * 8;
    half8 a1[4], a2[4];
#pragma unroll
    for (int kc = 0; kc < 4; ++kc) {
        a1[kc] = *(const half8*)(a1p + kc * 32);
        a2[kc] = *(const half8*)(a2p + kc * 32);
    }
#pragma unroll
    for (int ntile = 0; ntile < 8; ++ntile) {
        f32x4 acc = {0.f, 0.f, 0.f, 0.f};
#pragma unroll
        for (int kc = 0; kc < 4; ++kc) {
            half8 b1 = *(const half8*)(W1 + (size_t)((ntile * 4 + kc) * 64 + lane) * 8);
            acc = __builtin_amdgcn_mfma_f32_16x16x32_f16(a1[kc], b1, acc, 0, 0, 0);
            half8 b2 = *(const half8*)(W2 + (size_t)((ntile * 4 + kc) * 64 + lane) * 8);
            acc = __builtin_amdgcn_mfma_f32_16x16x32_f16(a2[kc], b2, acc, 0, 0, 0);
        }
        int colx = ntile * 16 + m;
        float bb = bias[colx];
#pragma unroll
        for (int r = 0; r < 4; ++r) {
            int rr = row0 + quad * 4 + r;
            if (rr < n) {
                float v = acc[r] + bb;
                if (layer == 2) {
                    Yf[(size_t)rr * 128 + colx] = v;
                } else {
                    Yh[(size_t)rr * 128 + colx] = __float2half(v);
                    int p8 = __builtin_amdgcn_cvt_pk_fp8_f32(v, v, 0, false);
                    Y8[(size_t)rr * 128 + colx] = (unsigned char)(p8 & 0xff);
                }
            }
        }
    }
}

extern "C" void kernel_launch(void* const* d_in, const int* in_sizes, int n_in,
                              void* d_out, int out_size, void* d_ws, size_t ws_size,
                              hipStream_t stream) {
    const float* x_d = (const float*)d_in[0];
    const float* x_g = (const float*)d_in[1];
    const int*   src = (const int*)d_in[2];
    const int*   dst = (const int*)d_in[3];
    float* out = (float*)d_out;

    char* ws = (char*)d_ws;
    int*            cnt   = (int*)(ws + OFF_CNT);
    int*            row   = (int*)(ws + OFF_ROW);
    int*            bsum  = (int*)(ws + OFF_BSUM);
    unsigned short* partD = (unsigned short*)(ws + OFF_PARTD);
    unsigned short* partG = (unsigned short*)(ws + OFF_PARTG);
    unsigned short* col   = (unsigned short*)(ws + OFF_COL);
    _Float16*       wsw   = (_Float16*)(ws + OFF_WSW);
    __half*         xd_h  = (__half*)(ws + OFF_XDH);
    __half*         xg_h  = (__half*)(ws + OFF_XGH);
    unsigned char*  x8d   = (unsigned char*)(ws + OFF_X8D);
    unsigned char*  x8g   = (unsigned char*)(ws + OFF_X8G);
    __half*         md_h  = (__half*)(ws + OFF_MDH);
    __half*         mg_h  = (__half*)(ws + OFF_MGH);
    __half*         d1_h  = (__half*)(ws + OFF_D1H);
    __half*         g1_h  = (__half*)(ws + OFF_G1H);
    unsigned char*  d1_8  = (unsigned char*)(ws + OFF_D18);
    unsigned char*  g1_8  = (unsigned char*)(ws + OFF_G18);

    const int E = in_sizes[2];              // 1,000,000
    const int nblkD = (ND + 63) / 64;       // 391
    const int nblkG = (NG + 63) / 64;       // 313

    WPtrs wp;
    wp.w[0] = (const float*)d_in[4];   // w1_dg_l
    wp.w[1] = (const float*)d_in[6];   // w1_dg_r
    wp.w[2] = (const float*)d_in[7];   // w1_gd_l
    wp.w[3] = (const float*)d_in[9];   // w1_gd_r
    wp.w[4] = (const float*)d_in[10];  // w2_dg_l
    wp.w[5] = (const float*)d_in[12];  // w2_dg_r
    wp.w[6] = (const float*)d_in[13];  // w2_gd_l
    wp.w[7] = (const float*)d_in[15];  // w2_gd_r
    const float* b1_dg = (const float*)d_in[5];
    const float* b1_gd = (const float*)d_in[8];
    const float* b2_dg = (const float*)d_in[11];
    const float* b2_gd = (const float*)d_in[14];

    // 1. hist + prep (independent, disjoint block ranges)
    prep_hist<<<2 * NBLK + PREPB, 256, 0, stream>>>(x_d, x_g, xd_h, xg_h, x8d, x8g,
                                                    wp, wsw, src, dst, partD, partG, E);
    // 2-4. partial scan -> rowptr
    colscan2<<<(NTOT + 255) / 256, 256, 0, stream>>>(partD, partG, cnt);
    scan1<<<NSCAN_BLOCKS, 256, 0, stream>>>(cnt, row, bsum, NTOT);
    scan2<<<NSCAN_BLOCKS, 256, 0, stream>>>(row, bsum, NTOT, 2 * E);
    // 5. CSR fill
    fill2<<<2 * NBLK, 256, 0, stream>>>(src, dst, row, partD, partG, col, E);

    // 6-7. layer 1
    agg8m<<<(NTOT + 3) / 4, 256, 0, stream>>>(x8g, x8d, row, col, md_h, mg_h);
    GemmDual g1p;
    g1p.A1d = md_h; g1p.A2d = xd_h; g1p.W1d = wsw + 2 * 16384; g1p.W2d = wsw + 3 * 16384;
    g1p.biasd = b1_gd; g1p.Yfd = nullptr; g1p.Yhd = d1_h; g1p.Y8d = d1_8;
    g1p.A1g = mg_h; g1p.A2g = xg_h; g1p.W1g = wsw + 0 * 16384; g1p.W2g = wsw + 1 * 16384;
    g1p.biasg = b1_dg; g1p.Yfg = nullptr; g1p.Yhg = g1_h; g1p.Y8g = g1_8;
    gemm2<<<nblkD + nblkG, 256, 0, stream>>>(g1p, nblkD, 1);

    // 8-9. layer 2
    agg8m<<<(NTOT + 3) / 4, 256, 0, stream>>>(g1_8, d1_8, row, col, md_h, mg_h);
    GemmDual g2p;
    g2p.A1d = md_h; g2p.A2d = d1_h; g2p.W1d = wsw + 6 * 16384; g2p.W2d = wsw + 7 * 16384;
    g2p.biasd = b2_gd; g2p.Yfd = out; g2p.Yhd = nullptr; g2p.Y8d = nullptr;
    g2p.A1g = mg_h; g2p.A2g = g1_h; g2p.W1g = wsw + 4 * 16384; g2p.W2g = wsw + 5 * 16384;
    g2p.biasg = b2_dg; g2p.Yfg = out + (size_t)ND * 128; g2p.Yhg = nullptr; g2p.Y8g = nullptr;
    gemm2<<<nblkD + nblkG, 256, 0, stream>>>(g2p, nblkD, 2);
}